// Round 4
// baseline (345.100 us; speedup 1.0000x reference)
//
#include <hip/hip_runtime.h>

#define BATCH   1024
#define ASZ     256
#define EDIM    200
#define RDIM    200
#define HDIM    400
#define ACTDIM  400   // E+R
#define INDIM   800   // E+H+R
#define NRELS   500

#define BM 64
#define BN 64
#define BK 32

// ---------------------------------------------------------------------------
// K_zero: zero the split-K tile counters (1024 ints)
// ---------------------------------------------------------------------------
__global__ __launch_bounds__(1024) void k_zero(int* __restrict__ cnt)
{
    cnt[threadIdx.x] = 0;
}

// ---------------------------------------------------------------------------
// Split-K tiled fp32 GEMM with fused "last block reduces" epilogue.
// C[M,N] = op(A[M,K] @ B + bias).
// BT=0: B is [K,N].  BT=1: B is [N,K] (C = A @ B^T).
// GATHER=1: A is the virtual concat [ent_emb[e[m]] ; H[m] ; rel_emb[q[m]]].
// Grid: (ceil(N/BN), ceil(M/BM), KS). 256 thr, 4x4 microtile, BK=32, dbuf LDS.
// ---------------------------------------------------------------------------
template<int RELU, int BT, int GATHER>
__global__ __launch_bounds__(256) void k_gemm(
    const float* __restrict__ A, const float* __restrict__ Bm,
    const float* __restrict__ bias,
    float* __restrict__ C, float* __restrict__ Cp, int* __restrict__ cnt,
    int M, int N, int K, int kslice,
    const int* __restrict__ eidx, const int* __restrict__ qidx,
    const float* __restrict__ Hmat,
    const float* __restrict__ ent, const float* __restrict__ rel)
{
    __shared__ __align__(16) float As[2][BK][BM];
    __shared__ __align__(16) float Bs[2][BK][BN];
    __shared__ int e_s[BM], q_s[BM];
    __shared__ int lastFlag;

    const int t   = threadIdx.x;
    const int bn  = blockIdx.x * BN;
    const int bm  = blockIdx.y * BM;
    const int ks  = blockIdx.z;
    const int nks = gridDim.z;
    const int kbeg = ks * kslice;
    const int kend = min(K, kbeg + kslice);
    const int nk   = (kend - kbeg + BK - 1) / BK;

    if (GATHER) {
        if (t < BM) {
            int gm = bm + t;          // M == BATCH exactly
            e_s[t] = eidx[gm];
            q_s[t] = qidx[gm];
        }
        __syncthreads();
    }

    // loader geometry
    const int ar  = t >> 3;            // 0..31  (rows ar and ar+32)
    const int ak4 = (t & 7) * 4;       // 0,4,...,28
    const int bkr = t >> 4;            // 0..15  (k rows bkr, bkr+16)  [BT=0]
    const int bnc = (t & 15) * 4;      // 0..60                        [BT=0]

    float4 a0, a1, b0, b1;

    auto srcA = [&](int r, int gk) -> float4 {
        if (!GATHER) {
            return *(const float4*)(A + (long)(bm + r) * K + gk);
        } else {
            int c4 = gk >> 2;
            const float* p;
            if (c4 < 50)        p = ent  + (long)e_s[r] * EDIM + gk;
            else if (c4 < 150)  p = Hmat + (long)(bm + r) * HDIM + (gk - EDIM);
            else                p = rel  + (long)q_s[r] * RDIM + (gk - EDIM - HDIM);
            return *(const float4*)p;
        }
    };

    auto fetch = [&](int kt) {
        const int k0 = kbeg + kt * BK;
        {
            int gk = k0 + ak4;
            bool kok = (gk + 4 <= kend);
            a0 = kok ? srcA(ar, gk)      : make_float4(0.f, 0.f, 0.f, 0.f);
            a1 = kok ? srcA(ar + 32, gk) : make_float4(0.f, 0.f, 0.f, 0.f);
        }
        if (BT == 0) {
            int gk0 = k0 + bkr, gk1 = k0 + bkr + 16;
            int gn = bn + bnc;
            bool nok = (gn + 4 <= N);
            b0 = (nok && gk0 < kend) ? *(const float4*)(Bm + (long)gk0 * N + gn)
                                     : make_float4(0.f, 0.f, 0.f, 0.f);
            b1 = (nok && gk1 < kend) ? *(const float4*)(Bm + (long)gk1 * N + gn)
                                     : make_float4(0.f, 0.f, 0.f, 0.f);
        } else {
            int gn0 = bn + ar, gn1 = bn + ar + 32;
            int gk = k0 + ak4;
            bool kok = (gk + 4 <= kend);
            b0 = (kok && gn0 < N) ? *(const float4*)(Bm + (long)gn0 * K + gk)
                                  : make_float4(0.f, 0.f, 0.f, 0.f);
            b1 = (kok && gn1 < N) ? *(const float4*)(Bm + (long)gn1 * K + gk)
                                  : make_float4(0.f, 0.f, 0.f, 0.f);
        }
    };

    auto stage = [&](int buf) {
        As[buf][ak4 + 0][ar] = a0.x;  As[buf][ak4 + 1][ar] = a0.y;
        As[buf][ak4 + 2][ar] = a0.z;  As[buf][ak4 + 3][ar] = a0.w;
        As[buf][ak4 + 0][ar + 32] = a1.x;  As[buf][ak4 + 1][ar + 32] = a1.y;
        As[buf][ak4 + 2][ar + 32] = a1.z;  As[buf][ak4 + 3][ar + 32] = a1.w;
        if (BT == 0) {
            *(float4*)&Bs[buf][bkr][bnc]      = b0;
            *(float4*)&Bs[buf][bkr + 16][bnc] = b1;
        } else {
            Bs[buf][ak4 + 0][ar] = b0.x;  Bs[buf][ak4 + 1][ar] = b0.y;
            Bs[buf][ak4 + 2][ar] = b0.z;  Bs[buf][ak4 + 3][ar] = b0.w;
            Bs[buf][ak4 + 0][ar + 32] = b1.x;  Bs[buf][ak4 + 1][ar + 32] = b1.y;
            Bs[buf][ak4 + 2][ar + 32] = b1.z;  Bs[buf][ak4 + 3][ar + 32] = b1.w;
        }
    };

    float acc[4][4];
#pragma unroll
    for (int i = 0; i < 4; ++i)
#pragma unroll
        for (int j = 0; j < 4; ++j) acc[i][j] = 0.f;

    const int tm = t >> 4;   // 0..15
    const int tn = t & 15;   // 0..15

    fetch(0);
    stage(0);
    __syncthreads();

    for (int kt = 0; kt < nk; ++kt) {
        const int cur = kt & 1;
        if (kt + 1 < nk) fetch(kt + 1);

#pragma unroll
        for (int kk = 0; kk < BK; ++kk) {
            const float4 a4 = *(const float4*)&As[cur][kk][tm * 4];
            const float4 b4 = *(const float4*)&Bs[cur][kk][tn * 4];
            acc[0][0] = fmaf(a4.x, b4.x, acc[0][0]);
            acc[0][1] = fmaf(a4.x, b4.y, acc[0][1]);
            acc[0][2] = fmaf(a4.x, b4.z, acc[0][2]);
            acc[0][3] = fmaf(a4.x, b4.w, acc[0][3]);
            acc[1][0] = fmaf(a4.y, b4.x, acc[1][0]);
            acc[1][1] = fmaf(a4.y, b4.y, acc[1][1]);
            acc[1][2] = fmaf(a4.y, b4.z, acc[1][2]);
            acc[1][3] = fmaf(a4.y, b4.w, acc[1][3]);
            acc[2][0] = fmaf(a4.z, b4.x, acc[2][0]);
            acc[2][1] = fmaf(a4.z, b4.y, acc[2][1]);
            acc[2][2] = fmaf(a4.z, b4.z, acc[2][2]);
            acc[2][3] = fmaf(a4.z, b4.w, acc[2][3]);
            acc[3][0] = fmaf(a4.w, b4.x, acc[3][0]);
            acc[3][1] = fmaf(a4.w, b4.y, acc[3][1]);
            acc[3][2] = fmaf(a4.w, b4.z, acc[3][2]);
            acc[3][3] = fmaf(a4.w, b4.w, acc[3][3]);
        }

        if (kt + 1 < nk) {
            __syncthreads();
            stage(cur ^ 1);
            __syncthreads();
        }
    }

    const int gn0 = bn + tn * 4;

    if (nks == 1) {
#pragma unroll
        for (int i = 0; i < 4; ++i) {
            int gm = bm + tm * 4 + i;
            if (gm >= M || gn0 >= N) continue;
            float4 v = make_float4(acc[i][0], acc[i][1], acc[i][2], acc[i][3]);
            if (bias) {
                float4 bb = *(const float4*)(bias + gn0);
                v.x += bb.x; v.y += bb.y; v.z += bb.z; v.w += bb.w;
            }
            if (RELU) {
                v.x = fmaxf(v.x, 0.f); v.y = fmaxf(v.y, 0.f);
                v.z = fmaxf(v.z, 0.f); v.w = fmaxf(v.w, 0.f);
            }
            *(float4*)(C + (long)gm * N + gn0) = v;
        }
        return;
    }

    // ---- split-K: write raw partials, last block per tile reduces ----
    {
        float* dst = Cp + (long)ks * M * N;
#pragma unroll
        for (int i = 0; i < 4; ++i) {
            int gm = bm + tm * 4 + i;
            if (gm >= M || gn0 >= N) continue;
            *(float4*)(dst + (long)gm * N + gn0) =
                make_float4(acc[i][0], acc[i][1], acc[i][2], acc[i][3]);
        }
    }
    __threadfence();
    if (t == 0) {
        int tileId = blockIdx.y * gridDim.x + blockIdx.x;
        int old = atomicAdd(cnt + tileId, 1);
        lastFlag = (old == nks - 1);
    }
    __syncthreads();
    if (!lastFlag) return;
    __threadfence();   // acquire: other blocks' partials now visible

#pragma unroll
    for (int i = 0; i < 4; ++i) {
        int gm = bm + tm * 4 + i;
        if (gm >= M || gn0 >= N) continue;
        long off = (long)gm * N + gn0;
        float4 s = *(const float4*)(Cp + off);
        for (int k2 = 1; k2 < nks; ++k2) {
            float4 v = *(const float4*)(Cp + (long)k2 * M * N + off);
            s.x += v.x; s.y += v.y; s.z += v.z; s.w += v.w;
        }
        if (bias) {
            float4 bb = *(const float4*)(bias + gn0);
            s.x += bb.x; s.y += bb.y; s.z += bb.z; s.w += bb.w;
        }
        if (RELU) {
            s.x = fmaxf(s.x, 0.f); s.y = fmaxf(s.y, 0.f);
            s.z = fmaxf(s.z, 0.f); s.w = fmaxf(s.w, 0.f);
        }
        *(float4*)(C + off) = s;
    }
}

// ---------------------------------------------------------------------------
// K6: scores + masked softmax + entropy + fused rel-row softmax.
// 512 threads = 8 waves per batch row; each wave owns 32 actions; masked
// actions skipped (dot-1e31 == -1e31 exactly in fp32); 4 actions/iter.
// ---------------------------------------------------------------------------
__global__ __launch_bounds__(512) void k_scores(
    const float* __restrict__ X2,
    const int* __restrict__ r_space, const int* __restrict__ e_space,
    const int* __restrict__ amask,
    const float* __restrict__ rel_emb, const float* __restrict__ ent_emb,
    float* __restrict__ out_dist, float* __restrict__ out_ent,
    float* __restrict__ out_rel)
{
    int b = blockIdx.x, t = threadIdx.x;
    int wave = t >> 6, lane = t & 63;
    __shared__ __align__(16) float x2s[ACTDIM];
    __shared__ float sc[ASZ];
    __shared__ int   smask[ASZ];
    __shared__ float red[8];

    for (int i = t; i < ACTDIM; i += 512) x2s[i] = X2[(long)b * ACTDIM + i];

    int abase = wave * 32;
    int r_idx = 0, e_idx = 0, mk = 0;
    if (lane < 32) {
        long base = (long)b * ASZ + abase + lane;
        r_idx = r_space[base];
        e_idx = e_space[base];
        mk    = amask[base];
        smask[abase + lane] = mk;
    }
    __syncthreads();

    const float4* xp = (const float4*)x2s;   // 100 float4
    float4 xA = xp[lane];
    float4 xB = make_float4(0.f, 0.f, 0.f, 0.f);
    if (lane < 36) xB = xp[lane + 64];

#pragma unroll
    for (int i = 0; i < 8; ++i) {
        float s[4] = {0.f, 0.f, 0.f, 0.f};
#pragma unroll
        for (int j = 0; j < 4; ++j) {
            int a = 4 * i + j;
            int m0 = __shfl(mk, a);
            if (m0) {
                int r0 = __shfl(r_idx, a);
                int e0 = __shfl(e_idx, a);
                const float4* rp = (const float4*)(rel_emb + (long)r0 * RDIM);
                const float4* ep = (const float4*)(ent_emb + (long)e0 * EDIM);
                float4 v0 = (lane < 50) ? rp[lane] : ep[lane - 50];
                s[j] = v0.x * xA.x + v0.y * xA.y + v0.z * xA.z + v0.w * xA.w;
                if (lane < 36) {
                    float4 v1 = ep[lane + 14];
                    s[j] += v1.x * xB.x + v1.y * xB.y + v1.z * xB.z + v1.w * xB.w;
                }
            }
        }
#pragma unroll
        for (int off = 32; off > 0; off >>= 1) {
            s[0] += __shfl_xor(s[0], off);
            s[1] += __shfl_xor(s[1], off);
            s[2] += __shfl_xor(s[2], off);
            s[3] += __shfl_xor(s[3], off);
        }
        if (lane == 0) {
            sc[abase + 4 * i + 0] = s[0];
            sc[abase + 4 * i + 1] = s[1];
            sc[abase + 4 * i + 2] = s[2];
            sc[abase + 4 * i + 3] = s[3];
        }
    }
    __syncthreads();

    // ---- masked softmax over 256 actions (threads 0..255) ----
    float v = -3.4e38f;
    float evv = 0.f;
    if (t < ASZ) v = smask[t] ? sc[t] : -1e31f;

    float m = v;
#pragma unroll
    for (int off = 32; off > 0; off >>= 1) m = fmaxf(m, __shfl_xor(m, off));
    if (t < ASZ && lane == 0) red[wave] = m;
    __syncthreads();
    float mm = fmaxf(fmaxf(red[0], red[1]), fmaxf(red[2], red[3]));
    __syncthreads();

    if (t < ASZ) evv = expf(v - mm);
    float ss = evv;
#pragma unroll
    for (int off = 32; off > 0; off >>= 1) ss += __shfl_xor(ss, off);
    if (t < ASZ && lane == 0) red[wave] = ss;
    __syncthreads();
    float tot = red[0] + red[1] + red[2] + red[3];
    __syncthreads();

    float term = 0.f;
    if (t < ASZ) {
        float p = evv / tot;
        out_dist[(long)b * ASZ + t] = p;
        term = p * logf(p + 1e-20f);
    }
#pragma unroll
    for (int off = 32; off > 0; off >>= 1) term += __shfl_xor(term, off);
    if (t < ASZ && lane == 0) red[wave] = term;
    __syncthreads();
    if (t == 0) out_ent[b] = -(red[0] + red[1] + red[2] + red[3]);

    // ---- fused relation-attention softmax over out_rel row b (500) ----
    float* r = out_rel + (long)b * NRELS;
    float rv = (t < NRELS) ? r[t] : -3.4e38f;

    float rm = rv;
#pragma unroll
    for (int off = 32; off > 0; off >>= 1) rm = fmaxf(rm, __shfl_xor(rm, off));
    if (lane == 0) red[wave] = rm;
    __syncthreads();
    rm = fmaxf(fmaxf(fmaxf(red[0], red[1]), fmaxf(red[2], red[3])),
               fmaxf(fmaxf(red[4], red[5]), fmaxf(red[6], red[7])));
    __syncthreads();

    float rev = (t < NRELS) ? expf(rv - rm) : 0.f;
    float rs = rev;
#pragma unroll
    for (int off = 32; off > 0; off >>= 1) rs += __shfl_xor(rs, off);
    if (lane == 0) red[wave] = rs;
    __syncthreads();
    rs = red[0] + red[1] + red[2] + red[3] + red[4] + red[5] + red[6] + red[7];
    if (t < NRELS) r[t] = rev / rs;
}

// ---------------------------------------------------------------------------
extern "C" void kernel_launch(void* const* d_in, const int* in_sizes, int n_in,
                              void* d_out, int out_size, void* d_ws, size_t ws_size,
                              hipStream_t stream)
{
    const int*   e       = (const int*)  d_in[0];
    const int*   q       = (const int*)  d_in[1];
    const float* H       = (const float*)d_in[2];
    const int*   r_space = (const int*)  d_in[3];
    const int*   e_space = (const int*)  d_in[4];
    const int*   amask   = (const int*)  d_in[5];
    const float* ent     = (const float*)d_in[6];
    const float* rel     = (const float*)d_in[7];
    const float* W1      = (const float*)d_in[8];
    const float* b1      = (const float*)d_in[9];
    const float* W2      = (const float*)d_in[10];
    const float* b2      = (const float*)d_in[11];
    const float* Watt    = (const float*)d_in[12];
    const float* batt    = (const float*)d_in[13];

    float* out      = (float*)d_out;
    float* out_dist = out;                              // [1024,256]
    float* out_ent  = out + (long)BATCH * ASZ;          // [1024]
    float* out_rel  = out_ent + BATCH;                  // [1024,500]

    char* ws = (char*)d_ws;
    float* X1  = (float*)(ws + 0);          // 1,638,400
    float* X2  = (float*)(ws + 1638400);    // 1,638,400
    float* T   = (float*)(ws + 3276800);    //   819,200
    int*   cnt = (int*)  (ws + 4096000);    // 1024 ints (256 per gemm)
    float* Cp  = (float*)(ws + 4194304);    // split-K partials (<= 8.2 MB)

    const bool sk = ws_size >= (size_t)16777216;
    const int ks1 = sk ? 4 : 1, ks2 = sk ? 4 : 1, ks3 = sk ? 4 : 1, ks4 = sk ? 4 : 1;

    if (sk) k_zero<<<1, 1024, 0, stream>>>(cnt);

    // X1 = relu([ent(e)|H|rel(q)] @ W1 + b1)   [1024,400] K=800 (gather fused)
    k_gemm<1,0,1><<<dim3(7,16,ks1), 256, 0, stream>>>(
        nullptr, W1, b1, X1, Cp, cnt + 0,
        BATCH, ACTDIM, INDIM, INDIM/ks1, e, q, H, ent, rel);

    // X2 = X1 @ W2 + b2          [1024,400] K=400
    k_gemm<0,0,0><<<dim3(7,16,ks2), 256, 0, stream>>>(
        X1, W2, b2, X2, Cp, cnt + 256,
        BATCH, ACTDIM, ACTDIM, ACTDIM/ks2, nullptr, nullptr, nullptr, nullptr, nullptr);

    // T = X2 @ W_att + b_att     [1024,200] K=400
    k_gemm<0,0,0><<<dim3(4,16,ks3), 256, 0, stream>>>(
        X2, Watt, batt, T, Cp, cnt + 512,
        BATCH, RDIM, ACTDIM, ACTDIM/ks3, nullptr, nullptr, nullptr, nullptr, nullptr);

    // out_rel = T @ rel^T        [1024,500] K=200  (raw scores; softmax fused in k_scores)
    k_gemm<0,1,0><<<dim3(8,16,ks4), 256, 0, stream>>>(
        T, rel, nullptr, out_rel, Cp, cnt + 768,
        BATCH, NRELS, RDIM, RDIM/ks4, nullptr, nullptr, nullptr, nullptr, nullptr);

    k_scores<<<BATCH, 512, 0, stream>>>(X2, r_space, e_space, amask, rel, ent,
                                        out_dist, out_ent, out_rel);
}

// Round 5
// 126.036 us; speedup vs baseline: 2.7381x; 2.7381x over previous
//
#include <hip/hip_runtime.h>

#define BATCH   1024
#define ASZ     256
#define EDIM    200
#define RDIM    200
#define HDIM    400
#define ACTDIM  400   // E+R
#define INDIM   800   // E+H+R
#define NRELS   500

#define BM 64
#define BN 64
#define BK 32

// ---------------------------------------------------------------------------
// K0: X_in[b] = [entity_emb[e[b]] ; H[b] ; relation_emb[q[b]]]  (float4)
// ---------------------------------------------------------------------------
__global__ __launch_bounds__(256) void k_gather_concat(
    const int* __restrict__ e, const int* __restrict__ q,
    const float* __restrict__ H,
    const float* __restrict__ ent_emb, const float* __restrict__ rel_emb,
    float* __restrict__ Xin)
{
    int b = blockIdx.x;
    int t = threadIdx.x;
    const float4* E4 = (const float4*)(ent_emb + (long)e[b] * EDIM);  // 50
    const float4* Q4 = (const float4*)(rel_emb + (long)q[b] * RDIM);  // 50
    const float4* H4 = (const float4*)(H + (long)b * HDIM);           // 100
    float4* X4 = (float4*)(Xin + (long)b * INDIM);                    // 200
    for (int i = t; i < 200; i += 256) {
        float4 v = (i < 50) ? E4[i] : (i < 150) ? H4[i - 50] : Q4[i - 150];
        X4[i] = v;
    }
}

// ---------------------------------------------------------------------------
// Split-K tiled fp32 GEMM.  C[M,N] = op(A[M,K] @ B) (+bias, relu if nks==1).
// BT=0: B is [K,N].  BT=1: B is [N,K] (C = A @ B^T).
// Grid: (ceil(N/BN), ceil(M/BM), KS). If KS>1, raw partials go to Cp[ks] slabs.
// 256 threads, 4x4 microtile, BK=32, double-buffered LDS. NO in-kernel
// cross-block reduction (device-scope fences cost an L2 flush per block on
// 8-XCD CDNA4 — round-4 regression). Separate k_reduce instead.
// ---------------------------------------------------------------------------
template<int RELU, int BT>
__global__ __launch_bounds__(256) void k_gemm(
    const float* __restrict__ A, const float* __restrict__ Bm,
    const float* __restrict__ bias,
    float* __restrict__ C, float* __restrict__ Cp,
    int M, int N, int K, int kslice)
{
    __shared__ __align__(16) float As[2][BK][BM];
    __shared__ __align__(16) float Bs[2][BK][BN];

    const int t   = threadIdx.x;
    const int bn  = blockIdx.x * BN;
    const int bm  = blockIdx.y * BM;
    const int ks  = blockIdx.z;
    const int nks = gridDim.z;
    const int kbeg = ks * kslice;
    const int kend = min(K, kbeg + kslice);
    const int nk   = (kend - kbeg + BK - 1) / BK;

    // loader geometry
    const int ar  = t >> 3;            // 0..31  (rows ar and ar+32)
    const int ak4 = (t & 7) * 4;       // 0,4,...,28
    const int bkr = t >> 4;            // 0..15  (k rows bkr, bkr+16)  [BT=0]
    const int bnc = (t & 15) * 4;      // 0..60                        [BT=0]

    float4 a0, a1, b0, b1;

    auto fetch = [&](int kt) {
        const int k0 = kbeg + kt * BK;
        {
            int gm0 = bm + ar, gm1 = bm + ar + 32;
            int gk = k0 + ak4;
            bool kok = (gk + 4 <= kend);
            a0 = (kok && gm0 < M) ? *(const float4*)(A + (long)gm0 * K + gk)
                                  : make_float4(0.f, 0.f, 0.f, 0.f);
            a1 = (kok && gm1 < M) ? *(const float4*)(A + (long)gm1 * K + gk)
                                  : make_float4(0.f, 0.f, 0.f, 0.f);
        }
        if (BT == 0) {
            int gk0 = k0 + bkr, gk1 = k0 + bkr + 16;
            int gn = bn + bnc;
            bool nok = (gn + 4 <= N);
            b0 = (nok && gk0 < kend) ? *(const float4*)(Bm + (long)gk0 * N + gn)
                                     : make_float4(0.f, 0.f, 0.f, 0.f);
            b1 = (nok && gk1 < kend) ? *(const float4*)(Bm + (long)gk1 * N + gn)
                                     : make_float4(0.f, 0.f, 0.f, 0.f);
        } else {
            int gn0 = bn + ar, gn1 = bn + ar + 32;
            int gk = k0 + ak4;
            bool kok = (gk + 4 <= kend);
            b0 = (kok && gn0 < N) ? *(const float4*)(Bm + (long)gn0 * K + gk)
                                  : make_float4(0.f, 0.f, 0.f, 0.f);
            b1 = (kok && gn1 < N) ? *(const float4*)(Bm + (long)gn1 * K + gk)
                                  : make_float4(0.f, 0.f, 0.f, 0.f);
        }
    };

    auto stage = [&](int buf) {
        As[buf][ak4 + 0][ar] = a0.x;  As[buf][ak4 + 1][ar] = a0.y;
        As[buf][ak4 + 2][ar] = a0.z;  As[buf][ak4 + 3][ar] = a0.w;
        As[buf][ak4 + 0][ar + 32] = a1.x;  As[buf][ak4 + 1][ar + 32] = a1.y;
        As[buf][ak4 + 2][ar + 32] = a1.z;  As[buf][ak4 + 3][ar + 32] = a1.w;
        if (BT == 0) {
            *(float4*)&Bs[buf][bkr][bnc]      = b0;
            *(float4*)&Bs[buf][bkr + 16][bnc] = b1;
        } else {
            Bs[buf][ak4 + 0][ar] = b0.x;  Bs[buf][ak4 + 1][ar] = b0.y;
            Bs[buf][ak4 + 2][ar] = b0.z;  Bs[buf][ak4 + 3][ar] = b0.w;
            Bs[buf][ak4 + 0][ar + 32] = b1.x;  Bs[buf][ak4 + 1][ar + 32] = b1.y;
            Bs[buf][ak4 + 2][ar + 32] = b1.z;  Bs[buf][ak4 + 3][ar + 32] = b1.w;
        }
    };

    float acc[4][4];
#pragma unroll
    for (int i = 0; i < 4; ++i)
#pragma unroll
        for (int j = 0; j < 4; ++j) acc[i][j] = 0.f;

    const int tm = t >> 4;   // 0..15
    const int tn = t & 15;   // 0..15

    fetch(0);
    stage(0);
    __syncthreads();

    for (int kt = 0; kt < nk; ++kt) {
        const int cur = kt & 1;
        if (kt + 1 < nk) fetch(kt + 1);

#pragma unroll
        for (int kk = 0; kk < BK; ++kk) {
            const float4 a4 = *(const float4*)&As[cur][kk][tm * 4];
            const float4 b4 = *(const float4*)&Bs[cur][kk][tn * 4];
            acc[0][0] = fmaf(a4.x, b4.x, acc[0][0]);
            acc[0][1] = fmaf(a4.x, b4.y, acc[0][1]);
            acc[0][2] = fmaf(a4.x, b4.z, acc[0][2]);
            acc[0][3] = fmaf(a4.x, b4.w, acc[0][3]);
            acc[1][0] = fmaf(a4.y, b4.x, acc[1][0]);
            acc[1][1] = fmaf(a4.y, b4.y, acc[1][1]);
            acc[1][2] = fmaf(a4.y, b4.z, acc[1][2]);
            acc[1][3] = fmaf(a4.y, b4.w, acc[1][3]);
            acc[2][0] = fmaf(a4.z, b4.x, acc[2][0]);
            acc[2][1] = fmaf(a4.z, b4.y, acc[2][1]);
            acc[2][2] = fmaf(a4.z, b4.z, acc[2][2]);
            acc[2][3] = fmaf(a4.z, b4.w, acc[2][3]);
            acc[3][0] = fmaf(a4.w, b4.x, acc[3][0]);
            acc[3][1] = fmaf(a4.w, b4.y, acc[3][1]);
            acc[3][2] = fmaf(a4.w, b4.z, acc[3][2]);
            acc[3][3] = fmaf(a4.w, b4.w, acc[3][3]);
        }

        if (kt + 1 < nk) {
            __syncthreads();
            stage(cur ^ 1);
            __syncthreads();
        }
    }

    const int gn0 = bn + tn * 4;
    if (nks == 1) {
#pragma unroll
        for (int i = 0; i < 4; ++i) {
            int gm = bm + tm * 4 + i;
            if (gm >= M || gn0 >= N) continue;
            float4 v = make_float4(acc[i][0], acc[i][1], acc[i][2], acc[i][3]);
            if (bias) {
                float4 bb = *(const float4*)(bias + gn0);
                v.x += bb.x; v.y += bb.y; v.z += bb.z; v.w += bb.w;
            }
            if (RELU) {
                v.x = fmaxf(v.x, 0.f); v.y = fmaxf(v.y, 0.f);
                v.z = fmaxf(v.z, 0.f); v.w = fmaxf(v.w, 0.f);
            }
            *(float4*)(C + (long)gm * N + gn0) = v;
        }
    } else {
        float* dst = Cp + (long)ks * M * N;
#pragma unroll
        for (int i = 0; i < 4; ++i) {
            int gm = bm + tm * 4 + i;
            if (gm >= M || gn0 >= N) continue;
            float4 v = make_float4(acc[i][0], acc[i][1], acc[i][2], acc[i][3]);
            *(float4*)(dst + (long)gm * N + gn0) = v;
        }
    }
}

// ---------------------------------------------------------------------------
// Split-K reduce: C[m,n] = op(sum_ks Cp[ks][m][n] + bias[n])
// ---------------------------------------------------------------------------
template<int RELU, int HASBIAS>
__global__ __launch_bounds__(128) void k_reduce(
    const float* __restrict__ Cp, const float* __restrict__ bias,
    float* __restrict__ C, int M, int N, int nks)
{
    int m = blockIdx.x;
    int nf4 = N >> 2;
    for (int f = threadIdx.x; f < nf4; f += 128) {
        long off = (long)m * N + f * 4;
        float4 s = *(const float4*)(Cp + off);
        for (int ks = 1; ks < nks; ++ks) {
            float4 v = *(const float4*)(Cp + (long)ks * M * N + off);
            s.x += v.x; s.y += v.y; s.z += v.z; s.w += v.w;
        }
        if (HASBIAS) {
            float4 bb = *(const float4*)(bias + f * 4);
            s.x += bb.x; s.y += bb.y; s.z += bb.z; s.w += bb.w;
        }
        if (RELU) {
            s.x = fmaxf(s.x, 0.f); s.y = fmaxf(s.y, 0.f);
            s.z = fmaxf(s.z, 0.f); s.w = fmaxf(s.w, 0.f);
        }
        *(float4*)(C + off) = s;
    }
}

// ---------------------------------------------------------------------------
// K6: scores + masked softmax + entropy + fused rel-row softmax.
// 512 threads = 8 waves per batch row; each wave owns 32 actions; masked
// actions skipped (dot-1e31 == -1e31 exactly in fp32); 4 actions/iter.
// ---------------------------------------------------------------------------
__global__ __launch_bounds__(512) void k_scores(
    const float* __restrict__ X2,
    const int* __restrict__ r_space, const int* __restrict__ e_space,
    const int* __restrict__ amask,
    const float* __restrict__ rel_emb, const float* __restrict__ ent_emb,
    float* __restrict__ out_dist, float* __restrict__ out_ent,
    float* __restrict__ out_rel)
{
    int b = blockIdx.x, t = threadIdx.x;
    int wave = t >> 6, lane = t & 63;
    __shared__ __align__(16) float x2s[ACTDIM];
    __shared__ float sc[ASZ];
    __shared__ int   smask[ASZ];
    __shared__ float red[8];

    for (int i = t; i < ACTDIM; i += 512) x2s[i] = X2[(long)b * ACTDIM + i];

    int abase = wave * 32;
    int r_idx = 0, e_idx = 0, mk = 0;
    if (lane < 32) {
        long base = (long)b * ASZ + abase + lane;
        r_idx = r_space[base];
        e_idx = e_space[base];
        mk    = amask[base];
        smask[abase + lane] = mk;
    }
    __syncthreads();

    const float4* xp = (const float4*)x2s;   // 100 float4
    float4 xA = xp[lane];
    float4 xB = make_float4(0.f, 0.f, 0.f, 0.f);
    if (lane < 36) xB = xp[lane + 64];

#pragma unroll
    for (int i = 0; i < 8; ++i) {
        float s[4] = {0.f, 0.f, 0.f, 0.f};
#pragma unroll
        for (int j = 0; j < 4; ++j) {
            int a = 4 * i + j;
            int m0 = __shfl(mk, a);
            if (m0) {
                int r0 = __shfl(r_idx, a);
                int e0 = __shfl(e_idx, a);
                const float4* rp = (const float4*)(rel_emb + (long)r0 * RDIM);
                const float4* ep = (const float4*)(ent_emb + (long)e0 * EDIM);
                float4 v0 = (lane < 50) ? rp[lane] : ep[lane - 50];
                s[j] = v0.x * xA.x + v0.y * xA.y + v0.z * xA.z + v0.w * xA.w;
                if (lane < 36) {
                    float4 v1 = ep[lane + 14];
                    s[j] += v1.x * xB.x + v1.y * xB.y + v1.z * xB.z + v1.w * xB.w;
                }
            }
        }
#pragma unroll
        for (int off = 32; off > 0; off >>= 1) {
            s[0] += __shfl_xor(s[0], off);
            s[1] += __shfl_xor(s[1], off);
            s[2] += __shfl_xor(s[2], off);
            s[3] += __shfl_xor(s[3], off);
        }
        if (lane == 0) {
            sc[abase + 4 * i + 0] = s[0];
            sc[abase + 4 * i + 1] = s[1];
            sc[abase + 4 * i + 2] = s[2];
            sc[abase + 4 * i + 3] = s[3];
        }
    }
    __syncthreads();

    // ---- masked softmax over 256 actions (threads 0..255) ----
    float v = -3.4e38f;
    float evv = 0.f;
    if (t < ASZ) v = smask[t] ? sc[t] : -1e31f;

    float m = v;
#pragma unroll
    for (int off = 32; off > 0; off >>= 1) m = fmaxf(m, __shfl_xor(m, off));
    if (t < ASZ && lane == 0) red[wave] = m;
    __syncthreads();
    float mm = fmaxf(fmaxf(red[0], red[1]), fmaxf(red[2], red[3]));
    __syncthreads();

    if (t < ASZ) evv = expf(v - mm);
    float ss = evv;
#pragma unroll
    for (int off = 32; off > 0; off >>= 1) ss += __shfl_xor(ss, off);
    if (t < ASZ && lane == 0) red[wave] = ss;
    __syncthreads();
    float tot = red[0] + red[1] + red[2] + red[3];
    __syncthreads();

    float term = 0.f;
    if (t < ASZ) {
        float p = evv / tot;
        out_dist[(long)b * ASZ + t] = p;
        term = p * logf(p + 1e-20f);
    }
#pragma unroll
    for (int off = 32; off > 0; off >>= 1) term += __shfl_xor(term, off);
    if (t < ASZ && lane == 0) red[wave] = term;
    __syncthreads();
    if (t == 0) out_ent[b] = -(red[0] + red[1] + red[2] + red[3]);

    // ---- fused relation-attention softmax over out_rel row b (500) ----
    float* r = out_rel + (long)b * NRELS;
    float rv = (t < NRELS) ? r[t] : -3.4e38f;

    float rm = rv;
#pragma unroll
    for (int off = 32; off > 0; off >>= 1) rm = fmaxf(rm, __shfl_xor(rm, off));
    if (lane == 0) red[wave] = rm;
    __syncthreads();
    rm = fmaxf(fmaxf(fmaxf(red[0], red[1]), fmaxf(red[2], red[3])),
               fmaxf(fmaxf(red[4], red[5]), fmaxf(red[6], red[7])));
    __syncthreads();

    float rev = (t < NRELS) ? expf(rv - rm) : 0.f;
    float rs = rev;
#pragma unroll
    for (int off = 32; off > 0; off >>= 1) rs += __shfl_xor(rs, off);
    if (lane == 0) red[wave] = rs;
    __syncthreads();
    rs = red[0] + red[1] + red[2] + red[3] + red[4] + red[5] + red[6] + red[7];
    if (t < NRELS) r[t] = rev / rs;
}

// ---------------------------------------------------------------------------
extern "C" void kernel_launch(void* const* d_in, const int* in_sizes, int n_in,
                              void* d_out, int out_size, void* d_ws, size_t ws_size,
                              hipStream_t stream)
{
    const int*   e       = (const int*)  d_in[0];
    const int*   q       = (const int*)  d_in[1];
    const float* H       = (const float*)d_in[2];
    const int*   r_space = (const int*)  d_in[3];
    const int*   e_space = (const int*)  d_in[4];
    const int*   amask   = (const int*)  d_in[5];
    const float* ent     = (const float*)d_in[6];
    const float* rel     = (const float*)d_in[7];
    const float* W1      = (const float*)d_in[8];
    const float* b1      = (const float*)d_in[9];
    const float* W2      = (const float*)d_in[10];
    const float* b2      = (const float*)d_in[11];
    const float* Watt    = (const float*)d_in[12];
    const float* batt    = (const float*)d_in[13];

    float* out      = (float*)d_out;
    float* out_dist = out;                              // [1024,256]
    float* out_ent  = out + (long)BATCH * ASZ;          // [1024]
    float* out_rel  = out_ent + BATCH;                  // [1024,500]

    char* ws = (char*)d_ws;
    float* Xin = (float*)(ws + 0);          // 3,276,800
    float* X1  = (float*)(ws + 3276800);    // 1,638,400
    float* X2  = (float*)(ws + 4915200);    // 1,638,400
    float* T   = (float*)(ws + 6553600);    //   819,200
    float* Cp  = (float*)(ws + 7372800);    // up to 6,553,600 (split-K partials)

    const bool sk = ws_size >= (size_t)13926400;   // partials fit?
    const int ks1 = sk ? 4 : 1, ks2 = sk ? 4 : 1, ks3 = sk ? 4 : 1, ks4 = sk ? 2 : 1;

    k_gather_concat<<<BATCH, 256, 0, stream>>>(e, q, H, ent, rel, Xin);

    // X1 = relu(Xin @ W1 + b1)   [1024,400] K=800
    k_gemm<1,0><<<dim3(7,16,ks1), 256, 0, stream>>>(Xin, W1, b1, X1, Cp,
                                                    BATCH, ACTDIM, INDIM, INDIM/ks1);
    if (sk) k_reduce<1,1><<<BATCH, 128, 0, stream>>>(Cp, b1, X1, BATCH, ACTDIM, ks1);

    // X2 = X1 @ W2 + b2          [1024,400] K=400
    k_gemm<0,0><<<dim3(7,16,ks2), 256, 0, stream>>>(X1, W2, b2, X2, Cp,
                                                    BATCH, ACTDIM, ACTDIM, ACTDIM/ks2);
    if (sk) k_reduce<0,1><<<BATCH, 128, 0, stream>>>(Cp, b2, X2, BATCH, ACTDIM, ks2);

    // T = X2 @ W_att + b_att     [1024,200] K=400
    k_gemm<0,0><<<dim3(4,16,ks3), 256, 0, stream>>>(X2, Watt, batt, T, Cp,
                                                    BATCH, RDIM, ACTDIM, ACTDIM/ks3);
    if (sk) k_reduce<0,1><<<BATCH, 128, 0, stream>>>(Cp, batt, T, BATCH, RDIM, ks3);

    // out_rel = T @ rel^T        [1024,500] K=200  (raw scores; softmax fused in k_scores)
    k_gemm<0,1><<<dim3(8,16,ks4), 256, 0, stream>>>(T, rel, nullptr, out_rel, Cp,
                                                    BATCH, NRELS, RDIM, RDIM/ks4);
    if (sk) k_reduce<0,0><<<BATCH, 128, 0, stream>>>(Cp, nullptr, out_rel, BATCH, NRELS, ks4);

    k_scores<<<BATCH, 512, 0, stream>>>(X2, r_space, e_space, amask, rel, ent,
                                        out_dist, out_ent, out_rel);
}